// Round 7
// baseline (721.191 us; speedup 1.0000x reference)
//
#include <hip/hip_runtime.h>
#include <hip/hip_fp16.h>

// Exact-binned COO segment-sum, bucket-major, single-u32 payload, fp16 x & p:
//   payload = (float_bits(p) & ~8191) | (local_row & 8191), bucket = row>>13
//   fp16 p is lossless under the 13-bit truncation (10 mantissa bits kept).
//
// Pipeline (5 stream ops):
//   memsetAsync(ctrl 4KB)
//   convert   : x f32 -> xh fp16 (4 MB, L2-resident)
//   A1        : grid-stride: rows/cols/vals streamed, global hist (LDS->global),
//               xh gathered (8-deep MLP, no barriers), p written fp16;
//               LAST BLOCK does the exclusive scan -> starts/cursors
//   A2        : per-4096-nnz chunk: rows in regs, LDS counting sort by bucket,
//               p loaded coalesced fp16, packed, coalesced run-flush into g_w
//   phaseB    : one 1024-thr block per bucket: coalesced region read, LDS f32
//               accumulate, fused proj + inf-norm; LAST BLOCK writes out
//
// ctrl (u32): [0..255] hist | [256..511] starts | [512..767] cursors |
//             [768..769] maxslots | [770] done_A1 | [771] done_phaseB
// ws: ctrl 4KB | xh fp16[n] | g_ph fp16[nnz] | g_w u32[nnz]   (~124 MB)

#define CHUNK 4096
#define BUCKW 8192
#define KPT 16

#define LBAR() do { \
    asm volatile("s_waitcnt lgkmcnt(0)" ::: "memory"); \
    __builtin_amdgcn_s_barrier(); \
    asm volatile("" ::: "memory"); \
} while (0)

__global__ __launch_bounds__(256) void convert_kernel(
    const float* __restrict__ x, __half* __restrict__ xh, int n)
{
    int tid = blockIdx.x * blockDim.x + threadIdx.x;
    int stride = gridDim.x * blockDim.x;
    int n8 = n >> 3;
    const float4* x4 = (const float4*)x;
    uint4* out4 = (uint4*)xh;
    for (int i = tid; i < n8; i += stride) {
        float4 a = x4[i * 2];
        float4 b = x4[i * 2 + 1];
        __half2 h0 = __floats2half2_rn(a.x, a.y);
        __half2 h1 = __floats2half2_rn(a.z, a.w);
        __half2 h2 = __floats2half2_rn(b.x, b.y);
        __half2 h3 = __floats2half2_rn(b.z, b.w);
        uint4 o;
        o.x = *reinterpret_cast<unsigned int*>(&h0);
        o.y = *reinterpret_cast<unsigned int*>(&h1);
        o.z = *reinterpret_cast<unsigned int*>(&h2);
        o.w = *reinterpret_cast<unsigned int*>(&h3);
        out4[i] = o;
    }
    if (tid == 0)
        for (int i = n8 << 3; i < n; ++i) xh[i] = __float2half(x[i]);
}

// A1: stream rows/cols/vals, hist, gather xh, write p (fp16); last block scans.
__global__ __launch_bounds__(256) void gathermul_kernel(
    const float* __restrict__ vals, const int* __restrict__ rows,
    const int* __restrict__ cols, const __half* __restrict__ xh,
    __half* __restrict__ g_ph, unsigned int* __restrict__ ctrl, int nnz)
{
    __shared__ unsigned int lh[256];
    __shared__ unsigned int wsum[4];
    __shared__ unsigned int isLast;
    const int t = threadIdx.x;
    lh[t] = 0u;
    __syncthreads();

    int tid = blockIdx.x * blockDim.x + t;
    int stride = gridDim.x * blockDim.x;
    int n8 = nnz >> 3;
    const int4* c4 = (const int4*)cols;
    const int4* r4 = (const int4*)rows;
    const float4* v4 = (const float4*)vals;
    uint4* p4 = (uint4*)g_ph;

    for (int i = tid; i < n8; i += stride) {
        int4 ca = c4[2 * i], cb = c4[2 * i + 1];
        int4 ra = r4[2 * i], rb = r4[2 * i + 1];
        float4 va = v4[2 * i], vb = v4[2 * i + 1];
        // 8 gathers in flight
        __half x0 = xh[ca.x], x1 = xh[ca.y], x2 = xh[ca.z], x3 = xh[ca.w];
        __half x4g = xh[cb.x], x5 = xh[cb.y], x6 = xh[cb.z], x7 = xh[cb.w];
        // histogram fills gather-latency bubbles
        atomicAdd(&lh[(unsigned)ra.x >> 13], 1u);
        atomicAdd(&lh[(unsigned)ra.y >> 13], 1u);
        atomicAdd(&lh[(unsigned)ra.z >> 13], 1u);
        atomicAdd(&lh[(unsigned)ra.w >> 13], 1u);
        atomicAdd(&lh[(unsigned)rb.x >> 13], 1u);
        atomicAdd(&lh[(unsigned)rb.y >> 13], 1u);
        atomicAdd(&lh[(unsigned)rb.z >> 13], 1u);
        atomicAdd(&lh[(unsigned)rb.w >> 13], 1u);
        __half2 h0 = __floats2half2_rn(va.x * __half2float(x0), va.y * __half2float(x1));
        __half2 h1 = __floats2half2_rn(va.z * __half2float(x2), va.w * __half2float(x3));
        __half2 h2 = __floats2half2_rn(vb.x * __half2float(x4g), vb.y * __half2float(x5));
        __half2 h3 = __floats2half2_rn(vb.z * __half2float(x6), vb.w * __half2float(x7));
        uint4 o;
        o.x = *reinterpret_cast<unsigned int*>(&h0);
        o.y = *reinterpret_cast<unsigned int*>(&h1);
        o.z = *reinterpret_cast<unsigned int*>(&h2);
        o.w = *reinterpret_cast<unsigned int*>(&h3);
        p4[i] = o;
    }
    if (tid == 0)
        for (int i = n8 << 3; i < nnz; ++i) {
            g_ph[i] = __float2half(vals[i] * __half2float(xh[cols[i]]));
            atomicAdd(&ctrl[(unsigned)rows[i] >> 13], 1u);
        }
    __syncthreads();
    unsigned int v = lh[t];
    if (v) atomicAdd(&ctrl[t], v);
    __threadfence();
    if (t == 0) isLast = (atomicAdd(&ctrl[770], 1u) == gridDim.x - 1) ? 1u : 0u;
    __syncthreads();
    if (isLast) {
        unsigned int hv = atomicAdd(&ctrl[t], 0u);  // coherent read
        unsigned int inc = hv;
        #pragma unroll
        for (int off = 1; off < 64; off <<= 1) {
            unsigned int nsh = __shfl_up(inc, off, 64);
            if ((t & 63) >= off) inc += nsh;
        }
        if ((t & 63) == 63) wsum[t >> 6] = inc;
        __syncthreads();
        unsigned int add = 0;
        for (int i = 0; i < (t >> 6); ++i) add += wsum[i];
        unsigned int excl = inc - hv + add;
        ctrl[256 + t] = excl;   // starts
        ctrl[512 + t] = excl;   // cursors
    }
}

// A2: per-chunk LDS counting sort of packed payload, coalesced run-flush.
__global__ __launch_bounds__(256) void sortflush_kernel(
    const int* __restrict__ rows, const __half* __restrict__ g_ph,
    unsigned int* __restrict__ ctrl, unsigned int* __restrict__ g_w, int nnz)
{
    __shared__ unsigned int wL[CHUNK];        // 16 KB packed payload
    __shared__ unsigned char bL[CHUNK];       // 4 KB bucket id
    __shared__ unsigned int hist[256], cursor[256];
    __shared__ int gstartI[256];
    __shared__ unsigned int wsum[4];

    unsigned int* gcursor = ctrl + 512;
    const int t = threadIdx.x;
    const long base = (long)blockIdx.x * CHUNK;
    const int cnt = (int)min((long)CHUNK, (long)nnz - base);
    const bool full = (cnt == CHUNK);

    hist[t] = 0u;
    LBAR();

    // rows -> registers; p (fp16) -> registers, matching 4-element grouping
    int rr[KPT];
    unsigned int pu[KPT / 2];   // 8 dwords = 16 halfs
    if (full) {
        const int4* rows4 = (const int4*)(rows + base);
        #pragma unroll
        for (int k4 = 0; k4 < 4; ++k4) {
            int4 r = rows4[t + 256 * k4];
            rr[k4 * 4 + 0] = r.x; rr[k4 * 4 + 1] = r.y;
            rr[k4 * 4 + 2] = r.z; rr[k4 * 4 + 3] = r.w;
        }
        const uint2* pp2 = (const uint2*)(g_ph + base);
        #pragma unroll
        for (int k4 = 0; k4 < 4; ++k4) {
            uint2 u = pp2[t + 256 * k4];
            pu[k4 * 2 + 0] = u.x;
            pu[k4 * 2 + 1] = u.y;
        }
    } else {
        #pragma unroll
        for (int k4 = 0; k4 < 4; ++k4)
            #pragma unroll
            for (int j = 0; j < 4; ++j) {
                int idx = (t + 256 * k4) * 4 + j;
                rr[k4 * 4 + j] = (idx < cnt) ? rows[base + idx] : -1;
            }
        #pragma unroll
        for (int k2 = 0; k2 < 8; ++k2) {
            int idx = (t + 256 * (k2 >> 1)) * 4 + (k2 & 1) * 2;
            unsigned short a = (idx < cnt) ? *(const unsigned short*)&g_ph[base + idx] : 0;
            unsigned short bq = (idx + 1 < cnt) ? *(const unsigned short*)&g_ph[base + idx + 1] : 0;
            pu[k2] = (unsigned int)a | ((unsigned int)bq << 16);
        }
    }

    // histogram
    #pragma unroll
    for (int k = 0; k < KPT; ++k)
        if (rr[k] >= 0) atomicAdd(&hist[(unsigned)rr[k] >> 13], 1u);
    LBAR();

    // chunk-local exclusive scan + global slot reservation
    unsigned int v = hist[t];
    unsigned int inc = v;
    #pragma unroll
    for (int off = 1; off < 64; off <<= 1) {
        unsigned int nsh = __shfl_up(inc, off, 64);
        if ((t & 63) >= off) inc += nsh;
    }
    if ((t & 63) == 63) wsum[t >> 6] = inc;
    LBAR();
    unsigned int add = 0;
    for (int i = 0; i < (t >> 6); ++i) add += wsum[i];
    unsigned int excl = inc - v + add;
    cursor[t] = excl;
    unsigned int gb = v ? atomicAdd(&gcursor[t], v) : 0u;
    gstartI[t] = (int)gb - (int)excl;
    LBAR();

    // pack + stage sorted-by-bucket in LDS
    #pragma unroll
    for (int k = 0; k < KPT; ++k) {
        int r = rr[k];
        if (r >= 0) {
            __half2 h = *reinterpret_cast<__half2*>(&pu[k >> 1]);
            float p = __half2float((k & 1) ? __high2half(h) : __low2half(h));
            unsigned int bk = (unsigned)r >> 13;
            unsigned int pos = atomicAdd(&cursor[bk], 1u);
            wL[pos] = (__float_as_uint(p) & ~8191u) | ((unsigned)r & 8191u);
            bL[pos] = (unsigned char)bk;
        }
    }
    LBAR();

    // run-structured coalesced flush into bucket-major regions
    #pragma unroll
    for (int k = 0; k < KPT; ++k) {
        int i = t + 256 * k;
        if (i < cnt) {
            unsigned int bk = bL[i];
            g_w[gstartI[bk] + i] = wL[i];
        }
    }
}

__global__ __launch_bounds__(1024) void phaseB_kernel(
    unsigned int* __restrict__ ctrl,
    const unsigned int* __restrict__ g_w,
    const float* __restrict__ bvec, const float* __restrict__ iy,
    int m, float* __restrict__ out)
{
    __shared__ float accum[BUCKW];   // 32 KB
    __shared__ float smp[16], smb[16];
    __shared__ unsigned int isLast;
    const unsigned int* starts = ctrl + 256;
    unsigned int* maxslots = ctrl + 768;
    const int t = threadIdx.x;
    const int bkt = blockIdx.x;

    for (int i = t; i < BUCKW; i += 1024) accum[i] = 0.f;
    __syncthreads();

    const unsigned int s = starts[bkt], e = starts[bkt + 1];
    unsigned int j = s + t;
    for (; j + 7u * 1024u < e; j += 8u * 1024u) {
        unsigned int w0 = g_w[j];
        unsigned int w1 = g_w[j + 1024];
        unsigned int w2 = g_w[j + 2048];
        unsigned int w3 = g_w[j + 3072];
        unsigned int w4 = g_w[j + 4096];
        unsigned int w5 = g_w[j + 5120];
        unsigned int w6 = g_w[j + 6144];
        unsigned int w7 = g_w[j + 7168];
        atomicAdd(&accum[w0 & 8191u], __uint_as_float(w0 & ~8191u));
        atomicAdd(&accum[w1 & 8191u], __uint_as_float(w1 & ~8191u));
        atomicAdd(&accum[w2 & 8191u], __uint_as_float(w2 & ~8191u));
        atomicAdd(&accum[w3 & 8191u], __uint_as_float(w3 & ~8191u));
        atomicAdd(&accum[w4 & 8191u], __uint_as_float(w4 & ~8191u));
        atomicAdd(&accum[w5 & 8191u], __uint_as_float(w5 & ~8191u));
        atomicAdd(&accum[w6 & 8191u], __uint_as_float(w6 & ~8191u));
        atomicAdd(&accum[w7 & 8191u], __uint_as_float(w7 & ~8191u));
    }
    for (; j < e; j += 1024u) {
        unsigned int w = g_w[j];
        atomicAdd(&accum[w & 8191u], __uint_as_float(w & ~8191u));
    }
    __syncthreads();

    // fused projection + inf-norm partial reduce (Ax stays in LDS)
    float mp = 0.f, mb = 0.f;
    long rb = (long)bkt * BUCKW;
    for (int i = t; i < BUCKW; i += 1024) {
        long row = rb + i;
        if (row < m) {
            float a = accum[i];
            float bb = bvec[row];
            float y = a - bb;
            float pr = y + iy[row] * fmaxf(-y, 0.f);
            mp = fmaxf(mp, fabsf(pr));
            mb = fmaxf(mb, fabsf(bb));
        }
    }
    #pragma unroll
    for (int off = 32; off > 0; off >>= 1) {
        mp = fmaxf(mp, __shfl_down(mp, off, 64));
        mb = fmaxf(mb, __shfl_down(mb, off, 64));
    }
    if ((t & 63) == 0) { smp[t >> 6] = mp; smb[t >> 6] = mb; }
    __syncthreads();
    if (t == 0) {
        #pragma unroll
        for (int w = 1; w < 16; ++w) { mp = fmaxf(mp, smp[w]); mb = fmaxf(mb, smb[w]); }
        atomicMax(&maxslots[0], __float_as_uint(mp));
        atomicMax(&maxslots[1], __float_as_uint(mb));
        __threadfence();
        isLast = (atomicAdd(&ctrl[771], 1u) == gridDim.x - 1) ? 1u : 0u;
    }
    __syncthreads();
    if (isLast && t == 0) {
        float p2 = __uint_as_float(atomicMax(&maxslots[0], 0u));
        float p3 = 1.f + __uint_as_float(atomicMax(&maxslots[1], 0u));
        out[0] = p2 / p3;
    }
}

// ---------- fallback path (tiny ws): direct scatter + reduce ----------
__global__ void fb_zero_kernel(float* __restrict__ ax, unsigned int* __restrict__ maxslots, int m) {
    int tid = blockIdx.x * blockDim.x + threadIdx.x;
    int stride = gridDim.x * blockDim.x;
    int m4 = m >> 2;
    float4* ax4 = reinterpret_cast<float4*>(ax);
    float4 z = make_float4(0.f, 0.f, 0.f, 0.f);
    for (int i = tid; i < m4; i += stride) ax4[i] = z;
    if (tid == 0) {
        for (int j = m4 << 2; j < m; ++j) ax[j] = 0.f;
        maxslots[0] = 0u; maxslots[1] = 0u;
    }
}

__global__ void fb_scatter_kernel(const float* __restrict__ vals, const int* __restrict__ rows,
                                  const int* __restrict__ cols, const float* __restrict__ x,
                                  float* __restrict__ ax, int nnz) {
    int i = (blockIdx.x * blockDim.x + threadIdx.x) << 2;
    if (i + 3 < nnz) {
        float4 v = *reinterpret_cast<const float4*>(vals + i);
        int4 r = *reinterpret_cast<const int4*>(rows + i);
        int4 c = *reinterpret_cast<const int4*>(cols + i);
        atomicAdd(&ax[r.x], v.x * x[c.x]);
        atomicAdd(&ax[r.y], v.y * x[c.y]);
        atomicAdd(&ax[r.z], v.z * x[c.z]);
        atomicAdd(&ax[r.w], v.w * x[c.w]);
    } else {
        for (; i < nnz; ++i) atomicAdd(&ax[rows[i]], vals[i] * x[cols[i]]);
    }
}

__global__ void fb_reduce_kernel(const float* __restrict__ ax, const float* __restrict__ b,
                                 const float* __restrict__ iy, unsigned int* __restrict__ maxslots, int m) {
    float mp = 0.f, mb = 0.f;
    int tid = blockIdx.x * blockDim.x + threadIdx.x;
    int stride = gridDim.x * blockDim.x;
    for (int i = tid; i < m; i += stride) {
        float bb = b[i];
        float y = ax[i] - bb;
        float p = y + iy[i] * fmaxf(-y, 0.f);
        mp = fmaxf(mp, fabsf(p));
        mb = fmaxf(mb, fabsf(bb));
    }
    #pragma unroll
    for (int off = 32; off > 0; off >>= 1) {
        mp = fmaxf(mp, __shfl_down(mp, off, 64));
        mb = fmaxf(mb, __shfl_down(mb, off, 64));
    }
    __shared__ float smp[4], smb[4];
    int wave = threadIdx.x >> 6;
    if ((threadIdx.x & 63) == 0) { smp[wave] = mp; smb[wave] = mb; }
    __syncthreads();
    if (threadIdx.x == 0) {
        for (int w = 1; w < (int)(blockDim.x >> 6); ++w) { mp = fmaxf(mp, smp[w]); mb = fmaxf(mb, smb[w]); }
        atomicMax(&maxslots[0], __float_as_uint(mp));
        atomicMax(&maxslots[1], __float_as_uint(mb));
    }
}

__global__ void fb_finalize_kernel(const unsigned int* __restrict__ maxslots, float* __restrict__ out) {
    if (threadIdx.x == 0 && blockIdx.x == 0) {
        float part2 = __uint_as_float(maxslots[0]);
        float part3 = 1.f + __uint_as_float(maxslots[1]);
        out[0] = part2 / part3;
    }
}

extern "C" void kernel_launch(void* const* d_in, const int* in_sizes, int n_in,
                              void* d_out, int out_size, void* d_ws, size_t ws_size,
                              hipStream_t stream) {
    const float* A_vals = (const float*)d_in[0];
    const float* b      = (const float*)d_in[1];
    // d_in[2] = c : unused
    const float* x      = (const float*)d_in[3];
    const float* Iy     = (const float*)d_in[4];
    const int* A_rows   = (const int*)d_in[5];
    const int* A_cols   = (const int*)d_in[6];

    int nnz = in_sizes[0];
    int m   = in_sizes[1];
    int n   = in_sizes[3];

    const int NC = (nnz + CHUNK - 1) / CHUNK;
    const int NB = (m + BUCKW - 1) / BUCKW;

    auto al = [](size_t v) { return (v + 255) & ~(size_t)255; };
    size_t ctrlBytes = 4096;
    size_t xhOff = al(ctrlBytes);
    size_t phOff = al(xhOff + (size_t)n * 2);
    size_t wOff  = al(phOff + (size_t)nnz * 2);
    size_t need  = wOff + (size_t)nnz * 4;

    float* out = (float*)d_out;

    if (need <= ws_size && NB <= 255 && nnz >= 8 && n >= 8) {
        unsigned int* ctrl = (unsigned int*)d_ws;
        __half* xh         = (__half*)((char*)d_ws + xhOff);
        __half* g_ph       = (__half*)((char*)d_ws + phOff);
        unsigned int* g_w  = (unsigned int*)((char*)d_ws + wOff);

        hipMemsetAsync(ctrl, 0, ctrlBytes, stream);
        convert_kernel<<<977, 256, 0, stream>>>(x, xh, n);
        gathermul_kernel<<<2048, 256, 0, stream>>>(A_vals, A_rows, A_cols, xh, g_ph, ctrl, nnz);
        sortflush_kernel<<<NC, 256, 0, stream>>>(A_rows, g_ph, ctrl, g_w, nnz);
        phaseB_kernel<<<NB, 1024, 0, stream>>>(ctrl, g_w, b, Iy, m, out);
    } else {
        float* ax = (float*)d_ws;
        unsigned int* maxslots = (unsigned int*)(ax + m);
        fb_zero_kernel<<<2048, 256, 0, stream>>>(ax, maxslots, m);
        int nthreads = (nnz + 3) >> 2;
        fb_scatter_kernel<<<(nthreads + 255) / 256, 256, 0, stream>>>(A_vals, A_rows, A_cols, x, ax, nnz);
        fb_reduce_kernel<<<2048, 256, 0, stream>>>(ax, b, Iy, maxslots, m);
        fb_finalize_kernel<<<1, 64, 0, stream>>>(maxslots, out);
    }
}

// Round 9
// 388.878 us; speedup vs baseline: 1.8545x; 1.8545x over previous
//
#include <hip/hip_runtime.h>
#include <hip/hip_fp16.h>

// Exact-binned COO segment-sum, bucket-major, single-u32 payload, fp16 x:
//   payload = (float_bits(p) & ~8191) | (local_row & 8191), bucket = row>>13
//
// Pipeline (4 stream ops):
//   memsetAsync(ctrl 4KB)
//   precount  : converts x->xh fp16 (grid-stride), then exact per-bucket row
//               counts (nt stream loads); LAST BLOCK scans -> starts/cursors
//   phaseA    : per-4096-nnz chunk: issue cols/rows/16 xh-gathers/vals early
//               (nt loads on streams so xh stays L2-resident), lgkm-only
//               barriers; LDS counting sort; nt coalesced run-flush into g_w
//   phaseB    : TWO blocks per bucket, split by row-half (bit 12 of local
//               row): each reads the whole bucket region (uint4 nt loads),
//               accumulates its half into 16KB LDS, fused proj + inf-norm on
//               its row half; LAST BLOCK writes out
//
// ctrl (u32): [0..255] hist | [256..511] starts | [512..767] cursors |
//             [768..769] maxslots | [770] done_pre | [771] done_phaseB
// ws: ctrl 4KB | xh fp16[n] | g_w u32[nnz]   (~84 MB)

#define CHUNK 4096
#define BUCKW 8192
#define KPT 16

typedef int   int4v   __attribute__((ext_vector_type(4)));
typedef float float4v __attribute__((ext_vector_type(4)));
typedef unsigned int uint4v __attribute__((ext_vector_type(4)));

#define LBAR() do { \
    asm volatile("s_waitcnt lgkmcnt(0)" ::: "memory"); \
    __builtin_amdgcn_s_barrier(); \
    asm volatile("" ::: "memory"); \
} while (0)

__global__ __launch_bounds__(256) void precount_kernel(
    const int* __restrict__ rows, const float* __restrict__ x,
    __half* __restrict__ xh, unsigned int* __restrict__ ctrl, int nnz, int n)
{
    __shared__ unsigned int lh[256];
    __shared__ unsigned int wsum[4];
    __shared__ unsigned int isLast;
    unsigned int* hist = ctrl;
    const int t = threadIdx.x;

    lh[t] = 0u;

    int tid = blockIdx.x * blockDim.x + t;
    int stride = gridDim.x * blockDim.x;

    // ---- part 0: convert x -> fp16 (xh), vectorized ----
    {
        int n8 = n >> 3;
        const float4v* x4 = (const float4v*)x;
        uint4v* out4 = (uint4v*)xh;
        for (int i = tid; i < n8; i += stride) {
            float4v a = __builtin_nontemporal_load(&x4[i * 2]);
            float4v b = __builtin_nontemporal_load(&x4[i * 2 + 1]);
            __half2 h0 = __floats2half2_rn(a.x, a.y);
            __half2 h1 = __floats2half2_rn(a.z, a.w);
            __half2 h2 = __floats2half2_rn(b.x, b.y);
            __half2 h3 = __floats2half2_rn(b.z, b.w);
            uint4v o;
            o.x = *reinterpret_cast<unsigned int*>(&h0);
            o.y = *reinterpret_cast<unsigned int*>(&h1);
            o.z = *reinterpret_cast<unsigned int*>(&h2);
            o.w = *reinterpret_cast<unsigned int*>(&h3);
            out4[i] = o;
        }
        if (tid == 0)
            for (int i = n8 << 3; i < n; ++i) xh[i] = __float2half(x[i]);
    }
    __syncthreads();

    // ---- part 1: row-bucket histogram ----
    int n4 = nnz >> 2;
    const int4v* r4 = (const int4v*)rows;
    for (int i = tid; i < n4; i += stride) {
        int4v r = __builtin_nontemporal_load(&r4[i]);
        atomicAdd(&lh[(unsigned)r.x >> 13], 1u);
        atomicAdd(&lh[(unsigned)r.y >> 13], 1u);
        atomicAdd(&lh[(unsigned)r.z >> 13], 1u);
        atomicAdd(&lh[(unsigned)r.w >> 13], 1u);
    }
    if (tid == 0)
        for (int i = n4 << 2; i < nnz; ++i) atomicAdd(&hist[(unsigned)rows[i] >> 13], 1u);
    __syncthreads();
    unsigned int v = lh[t];
    if (v) atomicAdd(&hist[t], v);
    __threadfence();
    if (t == 0) isLast = (atomicAdd(&ctrl[770], 1u) == gridDim.x - 1) ? 1u : 0u;
    __syncthreads();
    if (isLast) {
        unsigned int hv = atomicAdd(&hist[t], 0u);  // coherent read
        unsigned int inc = hv;
        #pragma unroll
        for (int off = 1; off < 64; off <<= 1) {
            unsigned int nsh = __shfl_up(inc, off, 64);
            if ((t & 63) >= off) inc += nsh;
        }
        if ((t & 63) == 63) wsum[t >> 6] = inc;
        __syncthreads();
        unsigned int add = 0;
        for (int i = 0; i < (t >> 6); ++i) add += wsum[i];
        unsigned int excl = inc - hv + add;
        ctrl[256 + t] = excl;   // starts
        ctrl[512 + t] = excl;   // cursors
    }
}

__global__ __launch_bounds__(256) void phaseA_kernel(
    const float* __restrict__ vals, const int* __restrict__ rows,
    const int* __restrict__ cols, const __half* __restrict__ xh,
    unsigned int* __restrict__ ctrl,
    unsigned int* __restrict__ g_w, int nnz)
{
    __shared__ unsigned int wL[CHUNK];        // 16 KB packed payload
    __shared__ unsigned char bL[CHUNK];       // 4 KB bucket id
    __shared__ unsigned int hist[256], cursor[256];
    __shared__ int gstartI[256];
    __shared__ unsigned int wsum[4];

    unsigned int* gcursor = ctrl + 512;
    const int t = threadIdx.x;
    const long base = (long)blockIdx.x * CHUNK;
    const int cnt = (int)min((long)CHUNK, (long)nnz - base);
    const bool full = (cnt == CHUNK);

    hist[t] = 0u;
    LBAR();

    // ---- issue all loads early: cols -> rows -> 16 xh-gathers -> vals ----
    // streams are nt (read-once) so xh stays L2-resident
    int cc[KPT]; int rr[KPT]; __half xv[KPT]; float vv[KPT];
    if (full) {
        const int4v* c4 = (const int4v*)(cols + base);
        #pragma unroll
        for (int k4 = 0; k4 < 4; ++k4) {
            int4v c = __builtin_nontemporal_load(&c4[t + 256 * k4]);
            cc[k4 * 4 + 0] = c.x; cc[k4 * 4 + 1] = c.y;
            cc[k4 * 4 + 2] = c.z; cc[k4 * 4 + 3] = c.w;
        }
        const int4v* rows4 = (const int4v*)(rows + base);
        #pragma unroll
        for (int k4 = 0; k4 < 4; ++k4) {
            int4v r = __builtin_nontemporal_load(&rows4[t + 256 * k4]);
            rr[k4 * 4 + 0] = r.x; rr[k4 * 4 + 1] = r.y;
            rr[k4 * 4 + 2] = r.z; rr[k4 * 4 + 3] = r.w;
        }
        #pragma unroll
        for (int k = 0; k < KPT; ++k) xv[k] = xh[cc[k]];   // 16 L2-hit gathers
        const float4v* v4 = (const float4v*)(vals + base);
        #pragma unroll
        for (int k4 = 0; k4 < 4; ++k4) {
            float4v a = __builtin_nontemporal_load(&v4[t + 256 * k4]);
            vv[k4 * 4 + 0] = a.x; vv[k4 * 4 + 1] = a.y;
            vv[k4 * 4 + 2] = a.z; vv[k4 * 4 + 3] = a.w;
        }
    } else {
        #pragma unroll
        for (int k4 = 0; k4 < 4; ++k4)
            #pragma unroll
            for (int j = 0; j < 4; ++j) {
                int idx = (t + 256 * k4) * 4 + j;
                int k = k4 * 4 + j;
                if (idx < cnt) { cc[k] = cols[base + idx]; rr[k] = rows[base + idx]; vv[k] = vals[base + idx]; }
                else { cc[k] = 0; rr[k] = -1; vv[k] = 0.f; }
            }
        #pragma unroll
        for (int k = 0; k < KPT; ++k) xv[k] = xh[cc[k]];
    }

    // ---- histogram (consumes rr only; gathers + vals stay in flight) ----
    #pragma unroll
    for (int k = 0; k < KPT; ++k)
        if (rr[k] >= 0) atomicAdd(&hist[(unsigned)rr[k] >> 13], 1u);
    LBAR();

    // ---- chunk-local exclusive scan + global slot reservation ----
    unsigned int v = hist[t];
    unsigned int inc = v;
    #pragma unroll
    for (int off = 1; off < 64; off <<= 1) {
        unsigned int nsh = __shfl_up(inc, off, 64);
        if ((t & 63) >= off) inc += nsh;
    }
    if ((t & 63) == 63) wsum[t >> 6] = inc;
    LBAR();
    unsigned int add = 0;
    for (int i = 0; i < (t >> 6); ++i) add += wsum[i];
    unsigned int excl = inc - v + add;
    cursor[t] = excl;
    unsigned int gb = v ? atomicAdd(&gcursor[t], v) : 0u;
    gstartI[t] = (int)gb - (int)excl;
    LBAR();

    // ---- pack: p = val*x[col], stage sorted-by-bucket in LDS ----
    #pragma unroll
    for (int k = 0; k < KPT; ++k) {
        int r = rr[k];
        if (r >= 0) {
            float p = vv[k] * __half2float(xv[k]);
            unsigned int bk = (unsigned)r >> 13;
            unsigned int pos = atomicAdd(&cursor[bk], 1u);
            wL[pos] = (__float_as_uint(p) & ~8191u) | ((unsigned)r & 8191u);
            bL[pos] = (unsigned char)bk;
        }
    }
    LBAR();

    // ---- run-structured coalesced nt flush into bucket-major regions ----
    #pragma unroll
    for (int k = 0; k < KPT; ++k) {
        int i = t + 256 * k;
        if (i < cnt) {
            unsigned int bk = bL[i];
            __builtin_nontemporal_store(wL[i], &g_w[gstartI[bk] + i]);
        }
    }
}

__global__ __launch_bounds__(1024) void phaseB_kernel(
    unsigned int* __restrict__ ctrl,
    const unsigned int* __restrict__ g_w,
    const float* __restrict__ bvec, const float* __restrict__ iy,
    int m, float* __restrict__ out)
{
    __shared__ float accum[BUCKW / 2];   // 16 KB (one row-half)
    __shared__ float smp[16], smb[16];
    __shared__ unsigned int isLast;
    const unsigned int* starts = ctrl + 256;
    unsigned int* maxslots = ctrl + 768;
    const int t = threadIdx.x;
    const int bkt = blockIdx.x >> 1;
    const unsigned int h = blockIdx.x & 1;          // row-half selector
    const unsigned int keepbit = h << 12;           // bit 12 of local row

    #pragma unroll
    for (int i = t; i < BUCKW / 2; i += 1024) accum[i] = 0.f;
    __syncthreads();

    const unsigned int s = starts[bkt], e = starts[bkt + 1];
    // head peel to 16B alignment
    unsigned int loA = (s + 3u) & ~3u;
    if (loA > e) loA = e;
    if (s + t < loA) {
        unsigned int w = g_w[s + t];
        if ((w & 4096u) == keepbit)
            atomicAdd(&accum[w & 4095u], __uint_as_float(w & ~8191u));
    }
    const unsigned int nvec = (e - loA) >> 2;
    const unsigned int e4 = loA + (nvec << 2);
    const uint4v* g4 = (const uint4v*)g_w;
    unsigned int k = (loA >> 2) + t;
    const unsigned int kend = (loA >> 2) + nvec;
    #define ACC(w) if (((w) & 4096u) == keepbit) atomicAdd(&accum[(w) & 4095u], __uint_as_float((w) & ~8191u))
    // 4-deep unrolled uint4 main loop (nt: read-once)
    for (; k + 3u * 1024u < kend; k += 4u * 1024u) {
        uint4v a = __builtin_nontemporal_load(&g4[k]);
        uint4v b = __builtin_nontemporal_load(&g4[k + 1024u]);
        uint4v c = __builtin_nontemporal_load(&g4[k + 2048u]);
        uint4v d = __builtin_nontemporal_load(&g4[k + 3072u]);
        ACC(a.x); ACC(a.y); ACC(a.z); ACC(a.w);
        ACC(b.x); ACC(b.y); ACC(b.z); ACC(b.w);
        ACC(c.x); ACC(c.y); ACC(c.z); ACC(c.w);
        ACC(d.x); ACC(d.y); ACC(d.z); ACC(d.w);
    }
    for (; k < kend; k += 1024u) {
        uint4v a = __builtin_nontemporal_load(&g4[k]);
        ACC(a.x); ACC(a.y); ACC(a.z); ACC(a.w);
    }
    #undef ACC
    // tail
    if (e4 + t < e) {
        unsigned int w = g_w[e4 + t];
        if ((w & 4096u) == keepbit)
            atomicAdd(&accum[w & 4095u], __uint_as_float(w & ~8191u));
    }
    __syncthreads();

    // fused projection + inf-norm partial reduce on this row half
    float mp = 0.f, mb = 0.f;
    long rb = (long)bkt * BUCKW + (long)h * (BUCKW / 2);
    #pragma unroll
    for (int i = t; i < BUCKW / 2; i += 1024) {
        long row = rb + i;
        if (row < m) {
            float a = accum[i];
            float bb = bvec[row];
            float y = a - bb;
            float pr = y + iy[row] * fmaxf(-y, 0.f);
            mp = fmaxf(mp, fabsf(pr));
            mb = fmaxf(mb, fabsf(bb));
        }
    }
    #pragma unroll
    for (int off = 32; off > 0; off >>= 1) {
        mp = fmaxf(mp, __shfl_down(mp, off, 64));
        mb = fmaxf(mb, __shfl_down(mb, off, 64));
    }
    if ((t & 63) == 0) { smp[t >> 6] = mp; smb[t >> 6] = mb; }
    __syncthreads();
    if (t == 0) {
        #pragma unroll
        for (int w = 1; w < 16; ++w) { mp = fmaxf(mp, smp[w]); mb = fmaxf(mb, smb[w]); }
        atomicMax(&maxslots[0], __float_as_uint(mp));
        atomicMax(&maxslots[1], __float_as_uint(mb));
        __threadfence();
        isLast = (atomicAdd(&ctrl[771], 1u) == gridDim.x - 1) ? 1u : 0u;
    }
    __syncthreads();
    if (isLast && t == 0) {
        float p2 = __uint_as_float(atomicMax(&maxslots[0], 0u));
        float p3 = 1.f + __uint_as_float(atomicMax(&maxslots[1], 0u));
        out[0] = p2 / p3;
    }
}

// ---------- fallback path (tiny ws): direct scatter + reduce ----------
__global__ void fb_zero_kernel(float* __restrict__ ax, unsigned int* __restrict__ maxslots, int m) {
    int tid = blockIdx.x * blockDim.x + threadIdx.x;
    int stride = gridDim.x * blockDim.x;
    int m4 = m >> 2;
    float4* ax4 = reinterpret_cast<float4*>(ax);
    float4 z = make_float4(0.f, 0.f, 0.f, 0.f);
    for (int i = tid; i < m4; i += stride) ax4[i] = z;
    if (tid == 0) {
        for (int j = m4 << 2; j < m; ++j) ax[j] = 0.f;
        maxslots[0] = 0u; maxslots[1] = 0u;
    }
}

__global__ void fb_scatter_kernel(const float* __restrict__ vals, const int* __restrict__ rows,
                                  const int* __restrict__ cols, const float* __restrict__ x,
                                  float* __restrict__ ax, int nnz) {
    int i = (blockIdx.x * blockDim.x + threadIdx.x) << 2;
    if (i + 3 < nnz) {
        float4 v = *reinterpret_cast<const float4*>(vals + i);
        int4 r = *reinterpret_cast<const int4*>(rows + i);
        int4 c = *reinterpret_cast<const int4*>(cols + i);
        atomicAdd(&ax[r.x], v.x * x[c.x]);
        atomicAdd(&ax[r.y], v.y * x[c.y]);
        atomicAdd(&ax[r.z], v.z * x[c.z]);
        atomicAdd(&ax[r.w], v.w * x[c.w]);
    } else {
        for (; i < nnz; ++i) atomicAdd(&ax[rows[i]], vals[i] * x[cols[i]]);
    }
}

__global__ void fb_reduce_kernel(const float* __restrict__ ax, const float* __restrict__ b,
                                 const float* __restrict__ iy, unsigned int* __restrict__ maxslots, int m) {
    float mp = 0.f, mb = 0.f;
    int tid = blockIdx.x * blockDim.x + threadIdx.x;
    int stride = gridDim.x * blockDim.x;
    for (int i = tid; i < m; i += stride) {
        float bb = b[i];
        float y = ax[i] - bb;
        float p = y + iy[i] * fmaxf(-y, 0.f);
        mp = fmaxf(mp, fabsf(p));
        mb = fmaxf(mb, fabsf(bb));
    }
    #pragma unroll
    for (int off = 32; off > 0; off >>= 1) {
        mp = fmaxf(mp, __shfl_down(mp, off, 64));
        mb = fmaxf(mb, __shfl_down(mb, off, 64));
    }
    __shared__ float smp[4], smb[4];
    int wave = threadIdx.x >> 6;
    if ((threadIdx.x & 63) == 0) { smp[wave] = mp; smb[wave] = mb; }
    __syncthreads();
    if (threadIdx.x == 0) {
        for (int w = 1; w < (int)(blockDim.x >> 6); ++w) { mp = fmaxf(mp, smp[w]); mb = fmaxf(mb, smb[w]); }
        atomicMax(&maxslots[0], __float_as_uint(mp));
        atomicMax(&maxslots[1], __float_as_uint(mb));
    }
}

__global__ void fb_finalize_kernel(const unsigned int* __restrict__ maxslots, float* __restrict__ out) {
    if (threadIdx.x == 0 && blockIdx.x == 0) {
        float part2 = __uint_as_float(maxslots[0]);
        float part3 = 1.f + __uint_as_float(maxslots[1]);
        out[0] = part2 / part3;
    }
}

extern "C" void kernel_launch(void* const* d_in, const int* in_sizes, int n_in,
                              void* d_out, int out_size, void* d_ws, size_t ws_size,
                              hipStream_t stream) {
    const float* A_vals = (const float*)d_in[0];
    const float* b      = (const float*)d_in[1];
    // d_in[2] = c : unused
    const float* x      = (const float*)d_in[3];
    const float* Iy     = (const float*)d_in[4];
    const int* A_rows   = (const int*)d_in[5];
    const int* A_cols   = (const int*)d_in[6];

    int nnz = in_sizes[0];
    int m   = in_sizes[1];
    int n   = in_sizes[3];

    const int NC = (nnz + CHUNK - 1) / CHUNK;
    const int NB = (m + BUCKW - 1) / BUCKW;

    auto al = [](size_t v) { return (v + 255) & ~(size_t)255; };
    size_t ctrlBytes = 4096;
    size_t xhOff = al(ctrlBytes);
    size_t wOff  = al(xhOff + (size_t)n * 2);
    size_t need  = wOff + (size_t)nnz * 4;

    float* out = (float*)d_out;

    if (need <= ws_size && NB <= 255 && nnz >= 4 && n >= 8) {
        unsigned int* ctrl = (unsigned int*)d_ws;
        __half* xh         = (__half*)((char*)d_ws + xhOff);
        unsigned int* g_w  = (unsigned int*)((char*)d_ws + wOff);

        (void)hipMemsetAsync(ctrl, 0, ctrlBytes, stream);
        precount_kernel<<<1024, 256, 0, stream>>>(A_rows, x, xh, ctrl, nnz, n);
        phaseA_kernel<<<NC, 256, 0, stream>>>(A_vals, A_rows, A_cols, xh, ctrl, g_w, nnz);
        phaseB_kernel<<<NB * 2, 1024, 0, stream>>>(ctrl, g_w, b, Iy, m, out);
    } else {
        float* ax = (float*)d_ws;
        unsigned int* maxslots = (unsigned int*)(ax + m);
        fb_zero_kernel<<<2048, 256, 0, stream>>>(ax, maxslots, m);
        int nthreads = (nnz + 3) >> 2;
        fb_scatter_kernel<<<(nthreads + 255) / 256, 256, 0, stream>>>(A_vals, A_rows, A_cols, x, ax, nnz);
        fb_reduce_kernel<<<2048, 256, 0, stream>>>(ax, b, Iy, maxslots, m);
        fb_finalize_kernel<<<1, 64, 0, stream>>>(maxslots, out);
    }
}

// Round 10
// 364.507 us; speedup vs baseline: 1.9785x; 1.0669x over previous
//
#include <hip/hip_runtime.h>
#include <hip/hip_fp16.h>

// Exact-binned COO segment-sum, bucket-major, single-u32 payload, fp16 x,
// DETERMINISTIC slot assignment (no global cursor atomics):
//   payload = (float_bits(p) & ~8191) | (local_row & 8191), bucket = row>>13
//
// Pipeline (5 stream ops):
//   memsetAsync(ctrl 4KB)
//   countchunks : one block per 4096-nnz chunk: rows -> LDS hist -> counts
//                 row (u16, coalesced); x->fp16 convert folded in (grid-stride)
//   scan        : one block per bucket: column of counts -> exact per-chunk
//                 prefix gstart[c][bk] (u32) + bucket totals; LAST block scans
//                 totals -> starts
//   phaseA      : per-chunk: issue cols/rows/16 xh-gathers/vals early (nt
//                 stream loads), lgkm-only barriers; LDS counting sort;
//                 destination base = starts[bk] + gstart[c][bk] (coalesced
//                 read, NO atomics); nt run-flush into bucket-major g_w
//   phaseB      : TWO blocks per bucket split by row-half (bit 12): uint4 nt
//                 region read, 16KB LDS accumulate, fused proj + inf-norm;
//                 LAST block writes out
//
// ctrl (u32): [0..255] totals | [256..511] starts | [512..767] unused |
//             [768..769] maxslots | [770] done_scan | [771] done_phaseB
// ws: ctrl 4KB | xh fp16[n] | counts u16[NC*256] | gstart u32[NC*256] |
//     g_w u32[nnz]   (~92 MB)

#define CHUNK 4096
#define BUCKW 8192
#define KPT 16
#define SCAN_PER 20   // supports NC <= 5120 (nnz <= 20.97M)

typedef int   int4v   __attribute__((ext_vector_type(4)));
typedef float float4v __attribute__((ext_vector_type(4)));
typedef unsigned int uint4v __attribute__((ext_vector_type(4)));

#define LBAR() do { \
    asm volatile("s_waitcnt lgkmcnt(0)" ::: "memory"); \
    __builtin_amdgcn_s_barrier(); \
    asm volatile("" ::: "memory"); \
} while (0)

__global__ __launch_bounds__(256) void countchunks_kernel(
    const int* __restrict__ rows, const float* __restrict__ x,
    __half* __restrict__ xh, unsigned short* __restrict__ counts,
    int nnz, int n)
{
    __shared__ unsigned int lh[256];
    const int t = threadIdx.x;
    lh[t] = 0u;

    // ---- x -> fp16 convert, grid-stride over whole grid ----
    {
        int tid = blockIdx.x * 256 + t;
        int stride = gridDim.x * 256;
        int n8 = n >> 3;
        const float4v* x4 = (const float4v*)x;
        uint4v* out4 = (uint4v*)xh;
        for (int i = tid; i < n8; i += stride) {
            float4v a = __builtin_nontemporal_load(&x4[i * 2]);
            float4v b = __builtin_nontemporal_load(&x4[i * 2 + 1]);
            __half2 h0 = __floats2half2_rn(a.x, a.y);
            __half2 h1 = __floats2half2_rn(a.z, a.w);
            __half2 h2 = __floats2half2_rn(b.x, b.y);
            __half2 h3 = __floats2half2_rn(b.z, b.w);
            uint4v o;
            o.x = *reinterpret_cast<unsigned int*>(&h0);
            o.y = *reinterpret_cast<unsigned int*>(&h1);
            o.z = *reinterpret_cast<unsigned int*>(&h2);
            o.w = *reinterpret_cast<unsigned int*>(&h3);
            out4[i] = o;
        }
        if (tid == 0)
            for (int i = n8 << 3; i < n; ++i) xh[i] = __float2half(x[i]);
    }
    __syncthreads();

    // ---- per-chunk histogram ----
    const long base = (long)blockIdx.x * CHUNK;
    const int cnt = (int)min((long)CHUNK, (long)nnz - base);
    if (cnt == CHUNK) {
        const int4v* r4 = (const int4v*)(rows + base);
        #pragma unroll
        for (int k4 = 0; k4 < 4; ++k4) {
            int4v r = __builtin_nontemporal_load(&r4[t + 256 * k4]);
            atomicAdd(&lh[(unsigned)r.x >> 13], 1u);
            atomicAdd(&lh[(unsigned)r.y >> 13], 1u);
            atomicAdd(&lh[(unsigned)r.z >> 13], 1u);
            atomicAdd(&lh[(unsigned)r.w >> 13], 1u);
        }
    } else {
        #pragma unroll
        for (int k = 0; k < KPT; ++k) {
            int idx = t + 256 * (k & 3);
            idx = (t + 256 * (k >> 2)) * 4 + (k & 3);   // match phaseA order (any order ok for counts)
            if (idx < cnt) atomicAdd(&lh[(unsigned)rows[base + idx] >> 13], 1u);
        }
    }
    __syncthreads();
    counts[(size_t)blockIdx.x * 256 + t] = (unsigned short)lh[t];
}

__global__ __launch_bounds__(256) void scan_kernel(
    const unsigned short* __restrict__ counts, unsigned int* __restrict__ gstart,
    unsigned int* __restrict__ ctrl, int NC)
{
    __shared__ unsigned int wsum[4];
    __shared__ unsigned int isLast;
    const int bk = blockIdx.x;
    const int t = threadIdx.x;

    // load my 20-element segment of this bucket's column into registers
    unsigned int lc[SCAN_PER];
    unsigned int s = 0;
    const int lo = t * SCAN_PER;
    #pragma unroll
    for (int k = 0; k < SCAN_PER; ++k) {
        int i = lo + k;
        lc[k] = (i < NC) ? (unsigned int)counts[(size_t)i * 256 + bk] : 0u;
        s += lc[k];
    }
    // block exclusive scan of per-thread sums
    unsigned int inc = s;
    #pragma unroll
    for (int off = 1; off < 64; off <<= 1) {
        unsigned int nsh = __shfl_up(inc, off, 64);
        if ((t & 63) >= off) inc += nsh;
    }
    if ((t & 63) == 63) wsum[t >> 6] = inc;
    __syncthreads();
    unsigned int add = 0;
    for (int i = 0; i < (t >> 6); ++i) add += wsum[i];
    unsigned int run = inc - s + add;      // exclusive prefix for this thread
    // write per-chunk prefix
    #pragma unroll
    for (int k = 0; k < SCAN_PER; ++k) {
        int i = lo + k;
        if (i < NC) { gstart[(size_t)i * 256 + bk] = run; run += lc[k]; }
    }
    // bucket total (thread 255 holds inclusive total)
    if (t == 255) atomicAdd(&ctrl[bk], inc + add);   // ctrl zeroed by memset
    __threadfence();
    if (t == 0) isLast = (atomicAdd(&ctrl[770], 1u) == gridDim.x - 1) ? 1u : 0u;
    __syncthreads();
    if (isLast) {
        unsigned int hv = atomicAdd(&ctrl[t], 0u);   // coherent read of totals
        unsigned int inc2 = hv;
        #pragma unroll
        for (int off = 1; off < 64; off <<= 1) {
            unsigned int nsh = __shfl_up(inc2, off, 64);
            if ((t & 63) >= off) inc2 += nsh;
        }
        if ((t & 63) == 63) wsum[t >> 6] = inc2;
        __syncthreads();
        unsigned int add2 = 0;
        for (int i = 0; i < (t >> 6); ++i) add2 += wsum[i];
        ctrl[256 + t] = inc2 - hv + add2;   // starts
    }
}

__global__ __launch_bounds__(256) void phaseA_kernel(
    const float* __restrict__ vals, const int* __restrict__ rows,
    const int* __restrict__ cols, const __half* __restrict__ xh,
    const unsigned int* __restrict__ ctrl, const unsigned int* __restrict__ gstart,
    unsigned int* __restrict__ g_w, int nnz)
{
    __shared__ unsigned int wL[CHUNK];        // 16 KB packed payload
    __shared__ unsigned char bL[CHUNK];       // 4 KB bucket id
    __shared__ unsigned int hist[256], cursor[256];
    __shared__ int gstartI[256];
    __shared__ unsigned int wsum[4];

    const int t = threadIdx.x;
    const long base = (long)blockIdx.x * CHUNK;
    const int cnt = (int)min((long)CHUNK, (long)nnz - base);
    const bool full = (cnt == CHUNK);

    hist[t] = 0u;
    LBAR();

    // ---- issue all loads early: cols -> rows -> 16 xh-gathers -> vals ----
    int cc[KPT]; int rr[KPT]; __half xv[KPT]; float vv[KPT];
    if (full) {
        const int4v* c4 = (const int4v*)(cols + base);
        #pragma unroll
        for (int k4 = 0; k4 < 4; ++k4) {
            int4v c = __builtin_nontemporal_load(&c4[t + 256 * k4]);
            cc[k4 * 4 + 0] = c.x; cc[k4 * 4 + 1] = c.y;
            cc[k4 * 4 + 2] = c.z; cc[k4 * 4 + 3] = c.w;
        }
        const int4v* rows4 = (const int4v*)(rows + base);
        #pragma unroll
        for (int k4 = 0; k4 < 4; ++k4) {
            int4v r = __builtin_nontemporal_load(&rows4[t + 256 * k4]);
            rr[k4 * 4 + 0] = r.x; rr[k4 * 4 + 1] = r.y;
            rr[k4 * 4 + 2] = r.z; rr[k4 * 4 + 3] = r.w;
        }
        #pragma unroll
        for (int k = 0; k < KPT; ++k) xv[k] = xh[cc[k]];   // 16 L2-hit gathers
        const float4v* v4 = (const float4v*)(vals + base);
        #pragma unroll
        for (int k4 = 0; k4 < 4; ++k4) {
            float4v a = __builtin_nontemporal_load(&v4[t + 256 * k4]);
            vv[k4 * 4 + 0] = a.x; vv[k4 * 4 + 1] = a.y;
            vv[k4 * 4 + 2] = a.z; vv[k4 * 4 + 3] = a.w;
        }
    } else {
        #pragma unroll
        for (int k4 = 0; k4 < 4; ++k4)
            #pragma unroll
            for (int j = 0; j < 4; ++j) {
                int idx = (t + 256 * k4) * 4 + j;
                int k = k4 * 4 + j;
                if (idx < cnt) { cc[k] = cols[base + idx]; rr[k] = rows[base + idx]; vv[k] = vals[base + idx]; }
                else { cc[k] = 0; rr[k] = -1; vv[k] = 0.f; }
            }
        #pragma unroll
        for (int k = 0; k < KPT; ++k) xv[k] = xh[cc[k]];
    }

    // ---- histogram (consumes rr only; gathers + vals stay in flight) ----
    #pragma unroll
    for (int k = 0; k < KPT; ++k)
        if (rr[k] >= 0) atomicAdd(&hist[(unsigned)rr[k] >> 13], 1u);
    LBAR();

    // ---- chunk-local exclusive scan; destination base from precomputed
    //      tables (deterministic, NO atomics) ----
    unsigned int v = hist[t];
    unsigned int inc = v;
    #pragma unroll
    for (int off = 1; off < 64; off <<= 1) {
        unsigned int nsh = __shfl_up(inc, off, 64);
        if ((t & 63) >= off) inc += nsh;
    }
    if ((t & 63) == 63) wsum[t >> 6] = inc;
    LBAR();
    unsigned int add = 0;
    for (int i = 0; i < (t >> 6); ++i) add += wsum[i];
    unsigned int excl = inc - v + add;
    cursor[t] = excl;
    unsigned int gb = ctrl[256 + t] + gstart[(size_t)blockIdx.x * 256 + t];
    gstartI[t] = (int)gb - (int)excl;
    LBAR();

    // ---- pack: p = val*x[col], stage sorted-by-bucket in LDS ----
    #pragma unroll
    for (int k = 0; k < KPT; ++k) {
        int r = rr[k];
        if (r >= 0) {
            float p = vv[k] * __half2float(xv[k]);
            unsigned int bk = (unsigned)r >> 13;
            unsigned int pos = atomicAdd(&cursor[bk], 1u);
            wL[pos] = (__float_as_uint(p) & ~8191u) | ((unsigned)r & 8191u);
            bL[pos] = (unsigned char)bk;
        }
    }
    LBAR();

    // ---- run-structured coalesced nt flush into bucket-major regions ----
    #pragma unroll
    for (int k = 0; k < KPT; ++k) {
        int i = t + 256 * k;
        if (i < cnt) {
            unsigned int bk = bL[i];
            __builtin_nontemporal_store(wL[i], &g_w[gstartI[bk] + i]);
        }
    }
}

__global__ __launch_bounds__(1024) void phaseB_kernel(
    unsigned int* __restrict__ ctrl,
    const unsigned int* __restrict__ g_w,
    const float* __restrict__ bvec, const float* __restrict__ iy,
    int m, float* __restrict__ out)
{
    __shared__ float accum[BUCKW / 2];   // 16 KB (one row-half)
    __shared__ float smp[16], smb[16];
    __shared__ unsigned int isLast;
    const unsigned int* starts = ctrl + 256;
    unsigned int* maxslots = ctrl + 768;
    const int t = threadIdx.x;
    const int bkt = blockIdx.x >> 1;
    const unsigned int h = blockIdx.x & 1;          // row-half selector
    const unsigned int keepbit = h << 12;           // bit 12 of local row

    #pragma unroll
    for (int i = t; i < BUCKW / 2; i += 1024) accum[i] = 0.f;
    __syncthreads();

    const unsigned int s = starts[bkt], e = starts[bkt + 1];
    // head peel to 16B alignment
    unsigned int loA = (s + 3u) & ~3u;
    if (loA > e) loA = e;
    if (s + t < loA) {
        unsigned int w = g_w[s + t];
        if ((w & 4096u) == keepbit)
            atomicAdd(&accum[w & 4095u], __uint_as_float(w & ~8191u));
    }
    const unsigned int nvec = (e - loA) >> 2;
    const unsigned int e4 = loA + (nvec << 2);
    const uint4v* g4 = (const uint4v*)g_w;
    unsigned int k = (loA >> 2) + t;
    const unsigned int kend = (loA >> 2) + nvec;
    #define ACC(w) if (((w) & 4096u) == keepbit) atomicAdd(&accum[(w) & 4095u], __uint_as_float((w) & ~8191u))
    for (; k + 3u * 1024u < kend; k += 4u * 1024u) {
        uint4v a = __builtin_nontemporal_load(&g4[k]);
        uint4v b = __builtin_nontemporal_load(&g4[k + 1024u]);
        uint4v c = __builtin_nontemporal_load(&g4[k + 2048u]);
        uint4v d = __builtin_nontemporal_load(&g4[k + 3072u]);
        ACC(a.x); ACC(a.y); ACC(a.z); ACC(a.w);
        ACC(b.x); ACC(b.y); ACC(b.z); ACC(b.w);
        ACC(c.x); ACC(c.y); ACC(c.z); ACC(c.w);
        ACC(d.x); ACC(d.y); ACC(d.z); ACC(d.w);
    }
    for (; k < kend; k += 1024u) {
        uint4v a = __builtin_nontemporal_load(&g4[k]);
        ACC(a.x); ACC(a.y); ACC(a.z); ACC(a.w);
    }
    #undef ACC
    if (e4 + t < e) {
        unsigned int w = g_w[e4 + t];
        if ((w & 4096u) == keepbit)
            atomicAdd(&accum[w & 4095u], __uint_as_float(w & ~8191u));
    }
    __syncthreads();

    // fused projection + inf-norm partial reduce on this row half
    float mp = 0.f, mb = 0.f;
    long rb = (long)bkt * BUCKW + (long)h * (BUCKW / 2);
    #pragma unroll
    for (int i = t; i < BUCKW / 2; i += 1024) {
        long row = rb + i;
        if (row < m) {
            float a = accum[i];
            float bb = bvec[row];
            float y = a - bb;
            float pr = y + iy[row] * fmaxf(-y, 0.f);
            mp = fmaxf(mp, fabsf(pr));
            mb = fmaxf(mb, fabsf(bb));
        }
    }
    #pragma unroll
    for (int off = 32; off > 0; off >>= 1) {
        mp = fmaxf(mp, __shfl_down(mp, off, 64));
        mb = fmaxf(mb, __shfl_down(mb, off, 64));
    }
    if ((t & 63) == 0) { smp[t >> 6] = mp; smb[t >> 6] = mb; }
    __syncthreads();
    if (t == 0) {
        #pragma unroll
        for (int w = 1; w < 16; ++w) { mp = fmaxf(mp, smp[w]); mb = fmaxf(mb, smb[w]); }
        atomicMax(&maxslots[0], __float_as_uint(mp));
        atomicMax(&maxslots[1], __float_as_uint(mb));
        __threadfence();
        isLast = (atomicAdd(&ctrl[771], 1u) == gridDim.x - 1) ? 1u : 0u;
    }
    __syncthreads();
    if (isLast && t == 0) {
        float p2 = __uint_as_float(atomicMax(&maxslots[0], 0u));
        float p3 = 1.f + __uint_as_float(atomicMax(&maxslots[1], 0u));
        out[0] = p2 / p3;
    }
}

// ---------- fallback path (tiny ws): direct scatter + reduce ----------
__global__ void fb_zero_kernel(float* __restrict__ ax, unsigned int* __restrict__ maxslots, int m) {
    int tid = blockIdx.x * blockDim.x + threadIdx.x;
    int stride = gridDim.x * blockDim.x;
    int m4 = m >> 2;
    float4* ax4 = reinterpret_cast<float4*>(ax);
    float4 z = make_float4(0.f, 0.f, 0.f, 0.f);
    for (int i = tid; i < m4; i += stride) ax4[i] = z;
    if (tid == 0) {
        for (int j = m4 << 2; j < m; ++j) ax[j] = 0.f;
        maxslots[0] = 0u; maxslots[1] = 0u;
    }
}

__global__ void fb_scatter_kernel(const float* __restrict__ vals, const int* __restrict__ rows,
                                  const int* __restrict__ cols, const float* __restrict__ x,
                                  float* __restrict__ ax, int nnz) {
    int i = (blockIdx.x * blockDim.x + threadIdx.x) << 2;
    if (i + 3 < nnz) {
        float4 v = *reinterpret_cast<const float4*>(vals + i);
        int4 r = *reinterpret_cast<const int4*>(rows + i);
        int4 c = *reinterpret_cast<const int4*>(cols + i);
        atomicAdd(&ax[r.x], v.x * x[c.x]);
        atomicAdd(&ax[r.y], v.y * x[c.y]);
        atomicAdd(&ax[r.z], v.z * x[c.z]);
        atomicAdd(&ax[r.w], v.w * x[c.w]);
    } else {
        for (; i < nnz; ++i) atomicAdd(&ax[rows[i]], vals[i] * x[cols[i]]);
    }
}

__global__ void fb_reduce_kernel(const float* __restrict__ ax, const float* __restrict__ b,
                                 const float* __restrict__ iy, unsigned int* __restrict__ maxslots, int m) {
    float mp = 0.f, mb = 0.f;
    int tid = blockIdx.x * blockDim.x + threadIdx.x;
    int stride = gridDim.x * blockDim.x;
    for (int i = tid; i < m; i += stride) {
        float bb = b[i];
        float y = ax[i] - bb;
        float p = y + iy[i] * fmaxf(-y, 0.f);
        mp = fmaxf(mp, fabsf(p));
        mb = fmaxf(mb, fabsf(bb));
    }
    #pragma unroll
    for (int off = 32; off > 0; off >>= 1) {
        mp = fmaxf(mp, __shfl_down(mp, off, 64));
        mb = fmaxf(mb, __shfl_down(mb, off, 64));
    }
    __shared__ float smp[4], smb[4];
    int wave = threadIdx.x >> 6;
    if ((threadIdx.x & 63) == 0) { smp[wave] = mp; smb[wave] = mb; }
    __syncthreads();
    if (threadIdx.x == 0) {
        for (int w = 1; w < (int)(blockDim.x >> 6); ++w) { mp = fmaxf(mp, smp[w]); mb = fmaxf(mb, smb[w]); }
        atomicMax(&maxslots[0], __float_as_uint(mp));
        atomicMax(&maxslots[1], __float_as_uint(mb));
    }
}

__global__ void fb_finalize_kernel(const unsigned int* __restrict__ maxslots, float* __restrict__ out) {
    if (threadIdx.x == 0 && blockIdx.x == 0) {
        float part2 = __uint_as_float(maxslots[0]);
        float part3 = 1.f + __uint_as_float(maxslots[1]);
        out[0] = part2 / part3;
    }
}

extern "C" void kernel_launch(void* const* d_in, const int* in_sizes, int n_in,
                              void* d_out, int out_size, void* d_ws, size_t ws_size,
                              hipStream_t stream) {
    const float* A_vals = (const float*)d_in[0];
    const float* b      = (const float*)d_in[1];
    // d_in[2] = c : unused
    const float* x      = (const float*)d_in[3];
    const float* Iy     = (const float*)d_in[4];
    const int* A_rows   = (const int*)d_in[5];
    const int* A_cols   = (const int*)d_in[6];

    int nnz = in_sizes[0];
    int m   = in_sizes[1];
    int n   = in_sizes[3];

    const int NC = (nnz + CHUNK - 1) / CHUNK;
    const int NB = (m + BUCKW - 1) / BUCKW;

    auto al = [](size_t v) { return (v + 255) & ~(size_t)255; };
    size_t ctrlBytes = 4096;
    size_t xhOff     = al(ctrlBytes);
    size_t countsOff = al(xhOff + (size_t)n * 2);
    size_t gstartOff = al(countsOff + (size_t)NC * 256 * 2);
    size_t wOff      = al(gstartOff + (size_t)NC * 256 * 4);
    size_t need      = wOff + (size_t)nnz * 4;

    float* out = (float*)d_out;

    if (need <= ws_size && NB <= 255 && NC <= 256 * SCAN_PER && nnz >= 4 && n >= 8) {
        unsigned int* ctrl     = (unsigned int*)d_ws;
        __half* xh             = (__half*)((char*)d_ws + xhOff);
        unsigned short* counts = (unsigned short*)((char*)d_ws + countsOff);
        unsigned int* gstart   = (unsigned int*)((char*)d_ws + gstartOff);
        unsigned int* g_w      = (unsigned int*)((char*)d_ws + wOff);

        (void)hipMemsetAsync(ctrl, 0, ctrlBytes, stream);
        countchunks_kernel<<<NC, 256, 0, stream>>>(A_rows, x, xh, counts, nnz, n);
        scan_kernel<<<256, 256, 0, stream>>>(counts, gstart, ctrl, NC);
        phaseA_kernel<<<NC, 256, 0, stream>>>(A_vals, A_rows, A_cols, xh, ctrl, gstart, g_w, nnz);
        phaseB_kernel<<<NB * 2, 1024, 0, stream>>>(ctrl, g_w, b, Iy, m, out);
    } else {
        float* ax = (float*)d_ws;
        unsigned int* maxslots = (unsigned int*)(ax + m);
        fb_zero_kernel<<<2048, 256, 0, stream>>>(ax, maxslots, m);
        int nthreads = (nnz + 3) >> 2;
        fb_scatter_kernel<<<(nthreads + 255) / 256, 256, 0, stream>>>(A_vals, A_rows, A_cols, x, ax, nnz);
        fb_reduce_kernel<<<2048, 256, 0, stream>>>(ax, b, Iy, maxslots, m);
        fb_finalize_kernel<<<1, 64, 0, stream>>>(maxslots, out);
    }
}